// Round 4
// baseline (115.658 us; speedup 1.0000x reference)
//
#include <hip/hip_runtime.h>
#include <hip/hip_bf16.h>

// Single-head causal attention. B=4, T=2048, E=768, H=64.
// x[4,2048,768] f32; Wk,Wq,Wv [768,64] f32. Out [4,2048,64] f32.
// R4: barrier-free attn. kws[key][h], vT[h][t], qws[row][h] are already in
// MFMA B/B/A fragment layout -> load fragments straight from global (16B/lane),
// no LDS staging, no __syncthreads, single-wave blocks (16 q-rows), split-K=4.
// Only P does a 2.3KB per-wave LDS round-trip (C->A layout). proj unchanged
// from R3 for clean attribution.

typedef __attribute__((ext_vector_type(8))) short short8;
typedef __attribute__((ext_vector_type(4))) float f32x4;

#define SPLIT_KB 4          // key-blocks (of 64) per split
#define MAX_SP 8            // ceil(32/4)

__device__ __forceinline__ unsigned short f2bf(float f) {
    union { float f; unsigned u; } v; v.f = f;
    unsigned r = v.u + 0x7fffu + ((v.u >> 16) & 1u);  // RNE
    return (unsigned short)(r >> 16);
}

// ---- projections, grid (256, 3): block = 32 rows x 64 cols of matrix my
__global__ __launch_bounds__(256) void proj_kernel(const float* __restrict__ x,
                                                   const float* __restrict__ Wk,
                                                   const float* __restrict__ Wq,
                                                   const float* __restrict__ Wv,
                                                   unsigned short* __restrict__ qws,
                                                   unsigned short* __restrict__ kws,
                                                   unsigned short* __restrict__ vT) {
    __shared__ unsigned short xs[32 * 72];    // [row][k]
    __shared__ unsigned short wsm[64 * 72];   // [n][k] (transposed W chunk)
    const float CSCALE = 1.4426950408889634f / 27.712812921102035f;  // log2e/sqrt(768)
    int tid = threadIdx.x;
    int lane = tid & 63, wave = tid >> 6;
    int quad = lane >> 4, l16 = lane & 15;
    int row0 = blockIdx.x * 32;
    int my = blockIdx.y;                      // 0=q 1=k 2=v
    const float* W = (my == 0) ? Wq : (my == 1) ? Wk : Wv;

    int xrow = tid >> 3, xcb = (tid & 7) * 8;
    int wn = tid & 63, wk0 = (tid >> 6) * 16;

    f32x4 acc[2];
    acc[0] = (f32x4)(0.f); acc[1] = (f32x4)(0.f);

    for (int kc = 0; kc < 12; ++kc) {
        __syncthreads();
        {   // stage x 32x64 f32 -> bf16
            const float* src = x + (size_t)(row0 + xrow) * 768 + kc * 64 + xcb;
            float4 f0 = *(const float4*)(src);
            float4 f1 = *(const float4*)(src + 4);
            short8 pk;
            pk[0] = (short)f2bf(f0.x); pk[1] = (short)f2bf(f0.y);
            pk[2] = (short)f2bf(f0.z); pk[3] = (short)f2bf(f0.w);
            pk[4] = (short)f2bf(f1.x); pk[5] = (short)f2bf(f1.y);
            pk[6] = (short)f2bf(f1.z); pk[7] = (short)f2bf(f1.w);
            *(short8*)&xs[xrow * 72 + xcb] = pk;
        }
        {   // stage W chunk transposed: wsm[n][k] = W[kc*64+k][n]
            float wv[16];
            for (int i = 0; i < 16; ++i)
                wv[i] = W[(size_t)(kc * 64 + wk0 + i) * 64 + wn];
            if (my == 0)
                for (int i = 0; i < 16; ++i) wv[i] *= CSCALE;
            short8 p0, p1;
            for (int i = 0; i < 8; ++i) { p0[i] = (short)f2bf(wv[i]); p1[i] = (short)f2bf(wv[8 + i]); }
            *(short8*)&wsm[wn * 72 + wk0] = p0;
            *(short8*)&wsm[wn * 72 + wk0 + 8] = p1;
        }
        __syncthreads();
        for (int kh = 0; kh < 2; ++kh) {
            int kk = kh * 32 + quad * 8;
            short8 bfr = *(const short8*)&wsm[(wave * 16 + l16) * 72 + kk];
            for (int mt = 0; mt < 2; ++mt) {
                short8 a = *(const short8*)&xs[(mt * 16 + l16) * 72 + kk];
                acc[mt] = __builtin_amdgcn_mfma_f32_16x16x32_bf16(a, bfr, acc[mt], 0, 0, 0);
            }
        }
    }
    __syncthreads();
    int n = wave * 16 + l16;
    if (my != 2) {
        unsigned short* dst = (my == 0) ? qws : kws;
        for (int mt = 0; mt < 2; ++mt)
            for (int j = 0; j < 4; ++j) {
                int rloc = mt * 16 + quad * 4 + j;
                dst[(size_t)(row0 + rloc) * 64 + n] = f2bf(acc[mt][j]);
            }
    } else {
        for (int mt = 0; mt < 2; ++mt)
            for (int j = 0; j < 4; ++j) {
                int rloc = mt * 16 + quad * 4 + j;
                wsm[n * 40 + rloc] = f2bf(acc[mt][j]);
            }
        __syncthreads();
        int bidx = row0 >> 11, t0 = row0 & 2047;
        int c = tid >> 2, rb = (tid & 3) * 8;
        *(short8*)&vT[((size_t)(bidx * 64 + c)) * 2048 + t0 + rb] =
            *(const short8*)&wsm[c * 40 + rb];
    }
}

// ---- barrier-free split-K flash attn: grid (128 tiles x 4 b x 8 sp), 64 thr
__global__ __launch_bounds__(64) void attn_split(const unsigned short* __restrict__ qws,
                                                 const unsigned short* __restrict__ kws,
                                                 const unsigned short* __restrict__ vT,
                                                 float* __restrict__ po,
                                                 float* __restrict__ pm,
                                                 float* __restrict__ pl,
                                                 float* __restrict__ out) {
    int bx = blockIdx.x, b = blockIdx.y, sp = blockIdx.z;
    int kbmax = (bx >> 2) + 1;                    // key-blocks for this 16-row tile
    int nsp = (kbmax + SPLIT_KB - 1) / SPLIT_KB;
    if (sp >= nsp) return;
    int kb_lo = sp * SPLIT_KB;
    int kb_hi = min(kb_lo + SPLIT_KB, kbmax);

    __shared__ unsigned short ps[16 * 72];        // per-wave P round-trip
    int lane = threadIdx.x & 63;
    int quad = lane >> 4, l16 = lane & 15;
    int q0 = bx * 16;

    // Q A-frags straight from global: A[m=l16][k=quad*8+j (+32*kh)]
    const unsigned short* qp = qws + ((size_t)b * 2048 + q0 + l16) * 64 + quad * 8;
    short8 aq0 = *(const short8*)(qp);
    short8 aq1 = *(const short8*)(qp + 32);

    f32x4 o_acc[4];
    for (int nt = 0; nt < 4; ++nt) o_acc[nt] = (f32x4)(0.f);
    float m_run[4], l_run[4];
    int row_g[4];
    for (int j = 0; j < 4; ++j) {
        m_run[j] = -1e30f; l_run[j] = 0.f;
        row_g[j] = q0 + quad * 4 + j;
    }

    for (int kb = kb_lo; kb < kb_hi; ++kb) {
        // QK^T: B[n=key][k=h] straight from kws[key][h]
        const unsigned short* kp =
            kws + ((size_t)b * 2048 + kb * 64 + l16) * 64 + quad * 8;
        f32x4 s[4];
        for (int nt = 0; nt < 4; ++nt) s[nt] = (f32x4)(0.f);
        for (int nt = 0; nt < 4; ++nt) {
            short8 bk0 = *(const short8*)(kp + (size_t)nt * 16 * 64);
            short8 bk1 = *(const short8*)(kp + (size_t)nt * 16 * 64 + 32);
            s[nt] = __builtin_amdgcn_mfma_f32_16x16x32_bf16(aq0, bk0, s[nt], 0, 0, 0);
            s[nt] = __builtin_amdgcn_mfma_f32_16x16x32_bf16(aq1, bk1, s[nt], 0, 0, 0);
        }
        if (kb == kbmax - 1) {                    // diagonal block only
            for (int nt = 0; nt < 4; ++nt) {
                int key = kb * 64 + nt * 16 + l16;
                for (int j = 0; j < 4; ++j)
                    if (key > row_g[j]) s[nt][j] = -1e30f;
            }
        }
        float mx[4], al[4], rs[4];
        for (int j = 0; j < 4; ++j)
            mx[j] = fmaxf(fmaxf(s[0][j], s[1][j]), fmaxf(s[2][j], s[3][j]));
        for (int off = 1; off < 16; off <<= 1)
            for (int j = 0; j < 4; ++j)
                mx[j] = fmaxf(mx[j], __shfl_xor(mx[j], off, 16));
        for (int j = 0; j < 4; ++j) {
            float mn = fmaxf(m_run[j], mx[j]);
            al[j] = exp2f(m_run[j] - mn);
            m_run[j] = mn;
            rs[j] = 0.f;
        }
        for (int nt = 0; nt < 4; ++nt)
            for (int j = 0; j < 4; ++j) {
                float p = exp2f(s[nt][j] - m_run[j]);
                rs[j] += p;
                ps[(quad * 4 + j) * 72 + nt * 16 + l16] = f2bf(p);
            }
        for (int off = 1; off < 16; off <<= 1)
            for (int j = 0; j < 4; ++j)
                rs[j] += __shfl_xor(rs[j], off, 16);
        for (int j = 0; j < 4; ++j) l_run[j] = l_run[j] * al[j] + rs[j];
        for (int nt = 0; nt < 4; ++nt)
            for (int j = 0; j < 4; ++j) o_acc[nt][j] *= al[j];
        // PV: A = P from ps, B[n=h][k=key] straight from vT[h][t]
        const unsigned short* vp =
            vT + ((size_t)b * 64 + l16) * 2048 + kb * 64 + quad * 8;
        for (int kh = 0; kh < 2; ++kh) {
            short8 ap = *(const short8*)&ps[l16 * 72 + kh * 32 + quad * 8];
            for (int nt = 0; nt < 4; ++nt) {
                short8 bv = *(const short8*)(vp + (size_t)nt * 16 * 2048 + kh * 32);
                o_acc[nt] = __builtin_amdgcn_mfma_f32_16x16x32_bf16(ap, bv, o_acc[nt], 0, 0, 0);
            }
        }
    }
    if (nsp == 1) {       // single split: write normalized output directly
        for (int nt = 0; nt < 4; ++nt)
            for (int j = 0; j < 4; ++j)
                out[((size_t)b * 2048 + row_g[j]) * 64 + nt * 16 + l16] =
                    o_acc[nt][j] / l_run[j];
        return;
    }
    int sbase = ((b * 128 + bx) * MAX_SP + sp) * 16;   // row-slot base
    for (int nt = 0; nt < 4; ++nt)
        for (int j = 0; j < 4; ++j) {
            int r = quad * 4 + j;
            po[(size_t)(sbase + r) * 64 + nt * 16 + l16] = o_acc[nt][j];
        }
    if (l16 == 0) {
        for (int j = 0; j < 4; ++j) {
            int r = quad * 4 + j;
            pm[sbase + r] = m_run[j];
            pl[sbase + r] = l_run[j];
        }
    }
}

// ---- combine splits: 1 wave per output row (rows with nsp==1 already done)
__global__ __launch_bounds__(256) void reduce_kernel(const float* __restrict__ po,
                                                     const float* __restrict__ pm,
                                                     const float* __restrict__ pl,
                                                     float* __restrict__ out) {
    int tid = threadIdx.x;
    int lane = tid & 63, wave = tid >> 6;
    int g = blockIdx.x * 4 + wave;        // row id [0, 8192)
    int b = g >> 11, t = g & 2047;
    int bx = t >> 4, r = t & 15;
    int kbmax = (bx >> 2) + 1;
    int nsp = (kbmax + SPLIT_KB - 1) / SPLIT_KB;
    if (nsp == 1) return;                 // written by attn_split directly
    int base = ((b * 128 + bx) * MAX_SP) * 16 + r;
    float mstar = -1e30f;
    for (int sp = 0; sp < nsp; ++sp)
        mstar = fmaxf(mstar, pm[base + sp * 16]);
    float acc = 0.f, lsum = 0.f;
    for (int sp = 0; sp < nsp; ++sp) {
        float w = exp2f(pm[base + sp * 16] - mstar);
        acc += w * po[(size_t)(base + sp * 16) * 64 + lane];
        lsum += w * pl[base + sp * 16];
    }
    out[(size_t)g * 64 + lane] = acc / lsum;
}

extern "C" void kernel_launch(void* const* d_in, const int* in_sizes, int n_in,
                              void* d_out, int out_size, void* d_ws, size_t ws_size,
                              hipStream_t stream) {
    const float* x  = (const float*)d_in[0];
    const float* Wk = (const float*)d_in[1];
    const float* Wq = (const float*)d_in[2];
    const float* Wv = (const float*)d_in[3];
    float* out = (float*)d_out;
    // ws layout (bytes):
    //   qws @ 0         (1 MB)
    //   kws @ 1048576   (1 MB)
    //   vT  @ 2097152   (1 MB)
    //   po  @ 3145728   (16.78 MB: 4b * 128bx * 8sp * 16 rows * 64 h * f32)
    //   pm  @ 19922944  (262144)
    //   pl  @ 20185088  (262144)   total ~20.4 MB
    char* w = (char*)d_ws;
    unsigned short* qws = (unsigned short*)w;
    unsigned short* kws = (unsigned short*)(w + 1048576);
    unsigned short* vT  = (unsigned short*)(w + 2097152);
    float* po = (float*)(w + 3145728);
    float* pm = (float*)(w + 19922944);
    float* pl = (float*)(w + 20185088);
    proj_kernel<<<dim3(256, 3), 256, 0, stream>>>(x, Wk, Wq, Wv, qws, kws, vT);
    attn_split<<<dim3(128, 4, MAX_SP), 64, 0, stream>>>(qws, kws, vT, po, pm, pl, out);
    reduce_kernel<<<2048, 256, 0, stream>>>(po, pm, pl, out);
}